// Round 9
// baseline (151.945 us; speedup 1.0000x reference)
//
#include <hip/hip_runtime.h>

#define BB 2
#define CC 2
#define NN 1024
#define HH 8
#define BCHN 32
#define SVN  (BCHN*NN)       // 32768
#define LOG2E 1.44269504f
#define X1S 520              // x1 LDS row stride in f16

typedef _Float16 f16x8 __attribute__((ext_vector_type(8)));
typedef _Float16 f16x4 __attribute__((ext_vector_type(4)));
typedef __fp16 h16x2 __attribute__((ext_vector_type(2)));   // cvt_pkrtz native type
typedef float f32x4 __attribute__((ext_vector_type(4)));

__device__ __forceinline__ float fexp2(float x) {
  float r; asm("v_exp_f32 %0, %1" : "=v"(r) : "v"(x)); return r;
}

// Direct global->LDS staging. LDS dest = wave-uniform base + lane*16B.
__device__ __forceinline__ void gl_lds16(const _Float16* g, _Float16* l) {
  __builtin_amdgcn_global_load_lds(
      (const __attribute__((address_space(1))) void*)g,
      (__attribute__((address_space(3))) void*)l, 16, 0, 0);
}

// Hp layouts are TILE-MAJOR: [bch][ktile=32][64 f][32 k] (4 KB contiguous tiles).

// ---------------- Fused layer-1 projection + prep (unchanged) ----------
__global__ __launch_bounds__(256) void proj1_fused(
    const float* __restrict__ x, const int* __restrict__ adj,
    const float* __restrict__ w1, const float* __restrict__ w2,
    const float* __restrict__ asrc, const float* __restrict__ adst,
    _Float16* __restrict__ w2T, unsigned long long* __restrict__ bmg,
    _Float16* __restrict__ HpT, float* __restrict__ s_out, float* __restrict__ d_out)
{
  __shared__ union {
    __align__(16) _Float16 tile[64*72];
    struct { float sp[4][32]; float sd[4][32]; } pr;
  } sm;
  const int bx = blockIdx.x;
  const int t = threadIdx.x;
  const int w = t >> 6, lane = t & 63;
  const int colr = lane & 15, quad = lane >> 4;

  if (bx < 1024) {
    const int bch = bx & 31;
    const int row0 = (bx >> 5) * 32;
    const int h = bch & 7; const int bc = bch >> 3; const int c = bc & 1;

    const float* Ar0 = x + ((size_t)bc*NN + row0 + colr)*64;
    const float* Ar1 = Ar0 + (size_t)16*64;
    const float* Bw  = w1 + ((size_t)(c*HH + h))*64*64 + w*16 + colr;

    f32x4 acc0 = {0.f,0.f,0.f,0.f}, acc1 = {0.f,0.f,0.f,0.f};
    #pragma unroll
    for (int kb = 0; kb < 64; kb += 32) {
      const float4 pa0 = *(const float4*)(Ar0 + kb + quad*8);
      const float4 pa1 = *(const float4*)(Ar0 + kb + quad*8 + 4);
      const float4 pb0 = *(const float4*)(Ar1 + kb + quad*8);
      const float4 pb1 = *(const float4*)(Ar1 + kb + quad*8 + 4);
      float bv[8];
      #pragma unroll
      for (int j = 0; j < 8; ++j) bv[j] = Bw[(size_t)(kb + quad*8 + j)*64];
      f16x8 a0, a1, bf;
      a0[0]=(_Float16)pa0.x; a0[1]=(_Float16)pa0.y; a0[2]=(_Float16)pa0.z; a0[3]=(_Float16)pa0.w;
      a0[4]=(_Float16)pa1.x; a0[5]=(_Float16)pa1.y; a0[6]=(_Float16)pa1.z; a0[7]=(_Float16)pa1.w;
      a1[0]=(_Float16)pb0.x; a1[1]=(_Float16)pb0.y; a1[2]=(_Float16)pb0.z; a1[3]=(_Float16)pb0.w;
      a1[4]=(_Float16)pb1.x; a1[5]=(_Float16)pb1.y; a1[6]=(_Float16)pb1.z; a1[7]=(_Float16)pb1.w;
      #pragma unroll
      for (int j = 0; j < 8; ++j) bf[j] = (_Float16)bv[j];
      acc0 = __builtin_amdgcn_mfma_f32_16x16x32_f16(a0, bf, acc0, 0, 0, 0);
      acc1 = __builtin_amdgcn_mfma_f32_16x16x32_f16(a1, bf, acc1, 0, 0, 0);
    }

    const float af  = asrc[(c*HH + h)*64 + w*16 + colr];
    const float bf_ = adst[(c*HH + h)*64 + w*16 + colr];
    _Float16* HT = HpT + (size_t)bch*65536 + (size_t)(row0 >> 5)*2048
                       + (size_t)(w*16 + colr)*32;

    #pragma unroll
    for (int mt = 0; mt < 2; ++mt) {
      const f32x4 a = mt ? acc1 : acc0;
      f16x4 hv;
      #pragma unroll
      for (int i = 0; i < 4; ++i) {
        const float v = a[i];
        hv[i] = (_Float16)v;
        const float ex = __expf(2.f*v);
        const float th = 1.f - 2.f/(ex + 1.f);         // tanh(v)
        float ps = th * af, pd = th * bf_;
        #pragma unroll
        for (int off = 1; off < 16; off <<= 1) {
          ps += __shfl_xor(ps, off);
          pd += __shfl_xor(pd, off);
        }
        if (colr == 0) {
          sm.pr.sp[w][mt*16 + quad*4 + i] = ps;
          sm.pr.sd[w][mt*16 + quad*4 + i] = pd;
        }
      }
      *(f16x4*)(HT + mt*16 + quad*4) = hv;
    }
    __syncthreads();
    if (t < 32) {
      const float sv = sm.pr.sp[0][t] + sm.pr.sp[1][t] + sm.pr.sp[2][t] + sm.pr.sp[3][t];
      const float dv = sm.pr.sd[0][t] + sm.pr.sd[1][t] + sm.pr.sd[2][t] + sm.pr.sd[3][t];
      s_out[bch*NN + row0 + t] = sv * LOG2E;
      d_out[bch*NN + row0 + t] = dv * LOG2E;
    }
  } else if (bx < 1152) {
    const int u = bx - 1024;
    const int ch = u >> 3, k0 = (u & 7)*64;
    const float* src = w2 + ((size_t)ch*512 + k0)*64;
    #pragma unroll
    for (int j = 0; j < 4; ++j) {
      const int uu = t + j*256;
      const int k = uu >> 4, seg = uu & 15;
      const float4 v = ((const float4*)src)[(size_t)k*16 + seg];
      sm.tile[(seg*4+0)*72 + k] = (_Float16)v.x;
      sm.tile[(seg*4+1)*72 + k] = (_Float16)v.y;
      sm.tile[(seg*4+2)*72 + k] = (_Float16)v.z;
      sm.tile[(seg*4+3)*72 + k] = (_Float16)v.w;
    }
    __syncthreads();
    _Float16* dst = w2T + (size_t)ch*32768;
    #pragma unroll
    for (int j = 0; j < 2; ++j) {
      const int uu = t + j*256;
      const int f = uu >> 3, seg = uu & 7;
      const f16x8 o = *(const f16x8*)&sm.tile[f*72 + seg*8];
      const int kk = k0 + seg*8;
      *(f16x8*)(dst + (size_t)(kk >> 5)*2048 + (size_t)f*32 + (kk & 31)) = o;
    }
  } else {
    const int g = (bx - 1152)*4 + w;
    const int base = g*32;
    #pragma unroll
    for (int jb = 0; jb < 4; ++jb) {
      int vals[8];
      #pragma unroll
      for (int i = 0; i < 8; ++i) {
        const int idx = base + jb*8 + i;
        const int b = idx >> 14;
        const int n = (idx >> 4) & (NN - 1);
        const int wd = idx & 15;
        vals[i] = adj[((size_t)b*NN + n)*NN + wd*64 + lane];
      }
      #pragma unroll
      for (int i = 0; i < 8; ++i) {
        const int idx = base + jb*8 + i;
        const int n = (idx >> 4) & (NN - 1);
        const int m = (idx & 15)*64 + lane;
        const unsigned long long bits = __ballot((vals[i] != 0) || (m == n));
        if (lane == 0) bmg[idx] = bits;
      }
    }
  }
}

// ---------------- Monster v6: exact vmcnt counting (in-loop VMEM = stage ops ONLY) ----
// d-slice staged to LDS in prologue (ds_read in loop -> lgkmcnt, not vmcnt).
// Depth-1 double buffer; lgkmcnt(0) guard before overwrite; vmcnt(4) == stage(ks) landed.
template<int LAYER>
__global__ __launch_bounds__(1024, 4) void attn_monster(
    const _Float16* __restrict__ HpTin, const float* __restrict__ s_arr,
    const float* __restrict__ d_arr, const unsigned long long* __restrict__ bmg,
    const _Float16* __restrict__ w2T, const float* __restrict__ asrc2,
    const float* __restrict__ adst2,
    _Float16* __restrict__ HpT2, float* __restrict__ s2, float* __restrict__ d2,
    float* __restrict__ out)
{
  __shared__ union {
    struct {
      __align__(16) _Float16 stg[2][16][2048];  // 128 KB B staging
      __align__(16) float dstg[16][512];        // 32 KB per-wave d slice
    } kl;                                       // k-loop phase: 160 KB
    struct {
      float obuf[2][8][16][68];                 // 69.6 KB partial O per kh
      float dsb[2][8][16];                      // row-sum partials per kh
      float spb[8][16], sdb[8][16];             // layer-2 score partials
      __align__(16) _Float16 x1[16*X1S];        // 16.6 KB elu'd concat tile
      __align__(16) _Float16 wstg[2][16][1024]; // 64 KB proj2 W staging
    } l1;
    struct { float mbuf[16][64]; float dsb[2][8][16]; } l2;
  } sm;

  const int bc = blockIdx.x;             // 0..3
  const int r0 = blockIdx.y * 16;
  const int t = threadIdx.x;
  const int wv = t >> 6;                 // 0..15
  const int h  = wv >> 1, kh = wv & 1;   // head, k-half
  const int lane = t & 63;
  const int colr = lane & 15, quad = lane >> 4;
  const int bch = bc*HH + h;
  const int b = bc >> 1, c = bc & 1;

  // full-range maxd (identical in both waves of a head -> shared offset)
  const float* dg = d_arr + (size_t)bch*NN;
  const float4* dg4 = (const float4*)dg;
  float mxl = -1e30f;
  #pragma unroll
  for (int j = 0; j < 4; ++j) {
    const float4 v = dg4[lane + 64*j];
    mxl = fmaxf(fmaxf(v.x, v.y), fmaxf(fmaxf(v.z, v.w), mxl));
  }
  #pragma unroll
  for (int off = 1; off < 64; off <<= 1) mxl = fmaxf(mxl, __shfl_xor(mxl, off));
  const float maxd = mxl;

  const int r = r0 + colr;
  const float s = s_arr[(size_t)bch*NN + r];
  const float so = s + maxd;
  const float offs = fmaxf(so, 0.2f*so);       // >= lrelu(s+d) for all d
  const float sA = s - offs, sB = 0.2f*s - offs;

  unsigned long long m[8];
  {
    const unsigned long long* bm = bmg + ((size_t)b*NN + r)*16 + kh*8;
    #pragma unroll
    for (int j = 0; j < 8; ++j) m[j] = bm[j];
  }

  // stage this wave's d half-slice (2 KB) into LDS: wave-private, no barrier needed
  {
    const float4* s4 = (const float4*)(dg + kh*512);
    const float4 v0 = s4[lane*2];
    const float4 v1 = s4[lane*2 + 1];
    *(float4*)&sm.kl.dstg[wv][lane*8]     = v0;
    *(float4*)&sm.kl.dstg[wv][lane*8 + 4] = v1;
  }

  const _Float16* strip = HpTin + (size_t)bch*65536 + (size_t)kh*32768;

  f32x4 acc[4];
  f32x4 accs = {0.f,0.f,0.f,0.f};
  #pragma unroll
  for (int ft = 0; ft < 4; ++ft) acc[ft] = (f32x4){0.f,0.f,0.f,0.f};
  f16x8 ones;
  #pragma unroll
  for (int i = 0; i < 8; ++i) ones[i] = (_Float16)1.f;

#define STAGE_B(tt) { \
    const _Float16* gs_ = strip + (tt)*2048 + lane*8; \
    _Float16* ls_ = &sm.kl.stg[(tt) & 1][wv][0]; \
    gl_lds16(gs_,        ls_); \
    gl_lds16(gs_ + 512,  ls_ + 512); \
    gl_lds16(gs_ + 1024, ls_ + 1024); \
    gl_lds16(gs_ + 1536, ls_ + 1536); }

  STAGE_B(0);

  #pragma unroll
  for (int ks = 0; ks < 16; ++ks) {
    if (ks < 15) {
      // guard: prior iteration's ds_reads of buf (ks+1)&1 complete before overwrite
      asm volatile("s_waitcnt lgkmcnt(0)" ::: "memory");
      STAGE_B(ks + 1);
      asm volatile("s_waitcnt vmcnt(4)" ::: "memory");   // stage(ks) landed (exact)
    } else {
      asm volatile("s_waitcnt vmcnt(0)" ::: "memory");
    }

    f16x8 Bc[4];
    #pragma unroll
    for (int ft = 0; ft < 4; ++ft)
      Bc[ft] = *(const f16x8*)&sm.kl.stg[ks & 1][wv][(ft*16 + colr)*32 + quad*8];

    // d from LDS: broadcast-uniform per quad (conflict-free), counts lgkm not vm
    const float* dls = &sm.kl.dstg[wv][ks*32 + quad*8];
    const float4 da0 = *(const float4*)dls;
    const float4 da1 = *(const float4*)(dls + 4);

    const unsigned mb = (unsigned)((m[ks >> 1] >> ((ks & 1)*32 + quad*8)) & 0xFFull);
    const float dd[8] = {da0.x, da0.y, da0.z, da0.w, da1.x, da1.y, da1.z, da1.w};
    union { f16x8 v; h16x2 hh[4]; } A;
    #pragma unroll
    for (int jp = 0; jp < 4; ++jp) {
      float p[2];
      #pragma unroll
      for (int jj = 0; jj < 2; ++jj) {
        const int j = jp*2 + jj;
        const float dj = dd[j];
        const float l = fmaxf(sA + dj, fmaf(0.2f, dj, sB));  // log2e-scaled domain
        p[jj] = ((mb >> j) & 1u) ? fexp2(l) : 0.f;
      }
      A.hh[jp] = __builtin_amdgcn_cvt_pkrtz(p[0], p[1]);
    }
    #pragma unroll
    for (int ft = 0; ft < 4; ++ft)
      acc[ft] = __builtin_amdgcn_mfma_f32_16x16x32_f16(A.v, Bc[ft], acc[ft], 0, 0, 0);
    accs = __builtin_amdgcn_mfma_f32_16x16x32_f16(A.v, ones, accs, 0, 0, 0);
  }
#undef STAGE_B

  __syncthreads();                        // staging buffers dead from here on

  if (LAYER == 1) {
    // phase 1: per-kh partial O / row-sums into separate slots; zero score partials
    if (t < 256) (&sm.l1.spb[0][0])[t] = 0.f;
    #pragma unroll
    for (int ft = 0; ft < 4; ++ft)
      #pragma unroll
      for (int i = 0; i < 4; ++i)
        sm.l1.obuf[kh][h][quad*4 + i][ft*16 + colr] = acc[ft][i];
    if (colr == 0) {
      #pragma unroll
      for (int i = 0; i < 4; ++i) sm.l1.dsb[kh][h][quad*4 + i] = accs[i];
    }
    __syncthreads();

    // phase 2: x1 = elu(O/dsum)
    {
      const int row = t >> 6;
      const int hp  = (t >> 3) & 7;
      const int f0  = (t & 7)*8;
      const float invd = 1.f / (sm.l1.dsb[0][hp][row] + sm.l1.dsb[1][hp][row]);
      const float* ob0 = &sm.l1.obuf[0][hp][row][f0];
      const float* ob1 = &sm.l1.obuf[1][hp][row][f0];
      f16x8 xo;
      #pragma unroll
      for (int j = 0; j < 8; ++j) {
        float v = (ob0[j] + ob1[j]) * invd;
        v = v > 0.f ? v : expm1f(v);
        xo[j] = (_Float16)v;
      }
      *(f16x8*)&sm.l1.x1[row*X1S + hp*64 + f0] = xo;
    }
    __syncthreads();

    // phase 3: proj2, wave (h,kh) computes f-tiles fb..fb+1; W staged depth-1
    // (in-loop VMEM = STAGE_W only -> vmcnt(2) exact)
    const int fb = kh*2;
    const _Float16* wstrip = w2T + (size_t)(c*HH + h)*32768 + fb*512;
    f32x4 acc2[2];
    acc2[0] = (f32x4){0.f,0.f,0.f,0.f}; acc2[1] = (f32x4){0.f,0.f,0.f,0.f};

#define STAGE_W(tt) { \
    const _Float16* gs_ = wstrip + (tt)*2048 + lane*8; \
    _Float16* ls_ = &sm.l1.wstg[(tt) & 1][wv][0]; \
    gl_lds16(gs_,       ls_); \
    gl_lds16(gs_ + 512, ls_ + 512); }

    STAGE_W(0);
    #pragma unroll
    for (int k2 = 0; k2 < 16; ++k2) {
      if (k2 < 15) {
        asm volatile("s_waitcnt lgkmcnt(0)" ::: "memory");
        STAGE_W(k2 + 1);
        asm volatile("s_waitcnt vmcnt(2)" ::: "memory");
      } else {
        asm volatile("s_waitcnt vmcnt(0)" ::: "memory");
      }
      f16x8 Wc[2];
      #pragma unroll
      for (int u = 0; u < 2; ++u)
        Wc[u] = *(const f16x8*)&sm.l1.wstg[k2 & 1][wv][(u*16 + colr)*32 + quad*8];
      const f16x8 Af = *(const f16x8*)&sm.l1.x1[colr*X1S + k2*32 + quad*8];
      #pragma unroll
      for (int u = 0; u < 2; ++u)
        acc2[u] = __builtin_amdgcn_mfma_f32_16x16x32_f16(Af, Wc[u], acc2[u], 0, 0, 0);
    }
#undef STAGE_W

    // scores: partial over this wave's 32 f, combined across wave pair via LDS atomics
    float af[2], bfv[2];
    #pragma unroll
    for (int u = 0; u < 2; ++u) {
      af[u]  = asrc2[(c*HH + h)*64 + (fb+u)*16 + colr];
      bfv[u] = adst2[(c*HH + h)*64 + (fb+u)*16 + colr];
    }
    #pragma unroll
    for (int i = 0; i < 4; ++i) {
      float ps = 0.f, pd = 0.f;
      #pragma unroll
      for (int u = 0; u < 2; ++u) {
        const float v = acc2[u][i];
        const float ex = __expf(2.f*v);
        const float th = 1.f - 2.f/(ex + 1.f);
        ps += th * af[u]; pd += th * bfv[u];
      }
      #pragma unroll
      for (int off = 1; off < 16; off <<= 1) {
        ps += __shfl_xor(ps, off);
        pd += __shfl_xor(pd, off);
      }
      if (colr == 0) {
        atomicAdd(&sm.l1.spb[h][quad*4 + i], ps);
        atomicAdd(&sm.l1.sdb[h][quad*4 + i], pd);
      }
    }
    // HpT2 tile-major write (disjoint f-tiles per wave)
    _Float16* H2 = HpT2 + (size_t)bch*65536 + (size_t)(r0 >> 5)*2048 + (r0 & 16) + quad*4;
    #pragma unroll
    for (int u = 0; u < 2; ++u) {
      f16x4 hv;
      #pragma unroll
      for (int i = 0; i < 4; ++i) hv[i] = (_Float16)acc2[u][i];
      *(f16x4*)(H2 + ((fb+u)*16 + colr)*32) = hv;
    }
    __syncthreads();
    if (t < 128) {
      const int hp = t >> 4, rr = t & 15;
      s2[(size_t)(bc*HH + hp)*NN + r0 + rr] = sm.l1.spb[hp][rr] * LOG2E;
      d2[(size_t)(bc*HH + hp)*NN + r0 + rr] = sm.l1.sdb[hp][rr] * LOG2E;
    }
  } else {
    // LAYER 2: zero mean buffer + per-kh row sums (kl buffers dead after sync above)
    sm.l2.mbuf[t >> 6][t & 63] = 0.f;
    if (colr == 0) {
      #pragma unroll
      for (int i = 0; i < 4; ++i) sm.l2.dsb[kh][h][quad*4 + i] = accs[i];
    }
    __syncthreads();
    float inv[4];
    #pragma unroll
    for (int i = 0; i < 4; ++i)
      inv[i] = 0.125f / (sm.l2.dsb[0][h][quad*4 + i] + sm.l2.dsb[1][h][quad*4 + i]);
    #pragma unroll
    for (int ft = 0; ft < 4; ++ft)
      #pragma unroll
      for (int i = 0; i < 4; ++i)
        atomicAdd(&sm.l2.mbuf[quad*4 + i][ft*16 + colr], acc[ft][i] * inv[i]);
    __syncthreads();
    out[((size_t)bc*NN + r0 + wv)*64 + lane] = sm.l2.mbuf[wv][lane];
  }
}

extern "C" void kernel_launch(void* const* d_in, const int* in_sizes, int n_in,
                              void* d_out, int out_size, void* d_ws, size_t ws_size,
                              hipStream_t stream)
{
  const float* x   = (const float*)d_in[0];
  const int*   adj = (const int*)d_in[1];
  const float* w1  = (const float*)d_in[2];
  const float* as1 = (const float*)d_in[3];
  const float* ad1 = (const float*)d_in[4];
  const float* w2  = (const float*)d_in[5];
  const float* as2 = (const float*)d_in[6];
  const float* ad2 = (const float*)d_in[7];

  char* w8 = (char*)d_ws;
  _Float16* HpT  = (_Float16*)(w8);                         // 4 MB  tile-major
  _Float16* HpT2 = (_Float16*)(w8 + (4u<<20));              // 4 MB  tile-major
  _Float16* w2T  = (_Float16*)(w8 + (8u<<20));              // 1 MB  tile-major
  float* s_v  = (float*)(w8 + (10u<<20));                   // 128 KB (log2e-scaled)
  float* d_v  = (float*)(w8 + (10u<<20) + SVN*4);           // 128 KB
  float* s2_v = (float*)(w8 + (10u<<20) + SVN*8);           // 128 KB
  float* d2_v = (float*)(w8 + (10u<<20) + SVN*12);          // 128 KB
  unsigned long long* bmg = (unsigned long long*)(w8 + (10u<<20) + SVN*16);  // 256 KB

  proj1_fused<<<1408, 256, 0, stream>>>(x, adj, w1, w2, as1, ad1, w2T, bmg, HpT, s_v, d_v);
  attn_monster<1><<<dim3(4, 64), 1024, 0, stream>>>(HpT, s_v, d_v, bmg, w2T, as2, ad2,
                                                    HpT2, s2_v, d2_v, (float*)d_out);
  attn_monster<2><<<dim3(4, 64), 1024, 0, stream>>>(HpT2, s2_v, d2_v, bmg, w2T, as2, ad2,
                                                    HpT2, s2_v, d2_v, (float*)d_out);
}

// Round 10
// 151.090 us; speedup vs baseline: 1.0057x; 1.0057x over previous
//
#include <hip/hip_runtime.h>

#define BB 2
#define CC 2
#define NN 1024
#define HH 8
#define BCHN 32
#define SVN  (BCHN*NN)       // 32768
#define LOG2E 1.44269504f

typedef _Float16 f16x8 __attribute__((ext_vector_type(8)));
typedef _Float16 f16x4 __attribute__((ext_vector_type(4)));
typedef __fp16 h16x2 __attribute__((ext_vector_type(2)));   // cvt_pkrtz native type
typedef float f32x4 __attribute__((ext_vector_type(4)));

__device__ __forceinline__ float fexp2(float x) {
  float r; asm("v_exp_f32 %0, %1" : "=v"(r) : "v"(x)); return r;
}

// Direct global->LDS staging. LDS dest = wave-uniform base + lane*16B.
__device__ __forceinline__ void gl_lds16(const _Float16* g, _Float16* l) {
  __builtin_amdgcn_global_load_lds(
      (const __attribute__((address_space(1))) void*)g,
      (__attribute__((address_space(3))) void*)l, 16, 0, 0);
}

// Hp/w2T tiles are 4KB [64 f][32 k] with PERMUTED in-tile order:
//   16B-chunk(f,k) = (f>>4)*64 + ((k>>3)&3)*16 + (f&15), elem j = k&7.
// => the MFMA fragment read for (ft, lane=(quad,colr)) is chunk ft*64 + lane,
//    i.e. addr = base + ft*1024B + lane*16B  — canonical lane-linear, zero
//    bank conflicts (old layout was 8-way conflicted: colr stride 64B).

// ---------------- Fused layer-1 projection + prep ----------
__global__ __launch_bounds__(256) void proj1_fused(
    const float* __restrict__ x, const int* __restrict__ adj,
    const float* __restrict__ w1, const float* __restrict__ w2,
    const float* __restrict__ asrc, const float* __restrict__ adst,
    _Float16* __restrict__ w2T, unsigned long long* __restrict__ bmg,
    _Float16* __restrict__ HpT, float* __restrict__ s_out, float* __restrict__ d_out)
{
  __shared__ union {
    __align__(16) _Float16 tile[64*72];
    struct { float sp[4][32]; float sd[4][32]; } pr;
  } sm;
  const int bx = blockIdx.x;
  const int t = threadIdx.x;
  const int w = t >> 6, lane = t & 63;
  const int colr = lane & 15, quad = lane >> 4;

  if (bx < 1024) {
    const int bch = bx & 31;
    const int row0 = (bx >> 5) * 32;
    const int h = bch & 7; const int bc = bch >> 3; const int c = bc & 1;

    const float* Ar0 = x + ((size_t)bc*NN + row0 + colr)*64;
    const float* Ar1 = Ar0 + (size_t)16*64;
    const float* Bw  = w1 + ((size_t)(c*HH + h))*64*64 + w*16 + colr;

    f32x4 acc0 = {0.f,0.f,0.f,0.f}, acc1 = {0.f,0.f,0.f,0.f};
    #pragma unroll
    for (int kb = 0; kb < 64; kb += 32) {
      const float4 pa0 = *(const float4*)(Ar0 + kb + quad*8);
      const float4 pa1 = *(const float4*)(Ar0 + kb + quad*8 + 4);
      const float4 pb0 = *(const float4*)(Ar1 + kb + quad*8);
      const float4 pb1 = *(const float4*)(Ar1 + kb + quad*8 + 4);
      float bv[8];
      #pragma unroll
      for (int j = 0; j < 8; ++j) bv[j] = Bw[(size_t)(kb + quad*8 + j)*64];
      f16x8 a0, a1, bf;
      a0[0]=(_Float16)pa0.x; a0[1]=(_Float16)pa0.y; a0[2]=(_Float16)pa0.z; a0[3]=(_Float16)pa0.w;
      a0[4]=(_Float16)pa1.x; a0[5]=(_Float16)pa1.y; a0[6]=(_Float16)pa1.z; a0[7]=(_Float16)pa1.w;
      a1[0]=(_Float16)pb0.x; a1[1]=(_Float16)pb0.y; a1[2]=(_Float16)pb0.z; a1[3]=(_Float16)pb0.w;
      a1[4]=(_Float16)pb1.x; a1[5]=(_Float16)pb1.y; a1[6]=(_Float16)pb1.z; a1[7]=(_Float16)pb1.w;
      #pragma unroll
      for (int j = 0; j < 8; ++j) bf[j] = (_Float16)bv[j];
      acc0 = __builtin_amdgcn_mfma_f32_16x16x32_f16(a0, bf, acc0, 0, 0, 0);
      acc1 = __builtin_amdgcn_mfma_f32_16x16x32_f16(a1, bf, acc1, 0, 0, 0);
    }

    const float af  = asrc[(c*HH + h)*64 + w*16 + colr];
    const float bf_ = adst[(c*HH + h)*64 + w*16 + colr];
    // permuted tile write: f = w*16+colr -> f>>4=w, f&15=colr; k = mt*16+quad*4+i
    _Float16* HT = HpT + (size_t)bch*65536 + (size_t)(row0 >> 5)*2048;

    #pragma unroll
    for (int mt = 0; mt < 2; ++mt) {
      const f32x4 a = mt ? acc1 : acc0;
      f16x4 hv;
      #pragma unroll
      for (int i = 0; i < 4; ++i) {
        const float v = a[i];
        hv[i] = (_Float16)v;
        const float ex = __expf(2.f*v);
        const float th = 1.f - 2.f/(ex + 1.f);         // tanh(v)
        float ps = th * af, pd = th * bf_;
        #pragma unroll
        for (int off = 1; off < 16; off <<= 1) {
          ps += __shfl_xor(ps, off);
          pd += __shfl_xor(pd, off);
        }
        if (colr == 0) {
          sm.pr.sp[w][mt*16 + quad*4 + i] = ps;
          sm.pr.sd[w][mt*16 + quad*4 + i] = pd;
        }
      }
      const int chunk = w*64 + (mt*2 + (quad >> 1))*16 + colr;
      *(f16x4*)(HT + chunk*8 + (quad & 1)*4) = hv;
    }
    __syncthreads();
    if (t < 32) {
      const float sv = sm.pr.sp[0][t] + sm.pr.sp[1][t] + sm.pr.sp[2][t] + sm.pr.sp[3][t];
      const float dv = sm.pr.sd[0][t] + sm.pr.sd[1][t] + sm.pr.sd[2][t] + sm.pr.sd[3][t];
      s_out[bch*NN + row0 + t] = sv * LOG2E;
      d_out[bch*NN + row0 + t] = dv * LOG2E;
    }
  } else if (bx < 1152) {
    const int u = bx - 1024;
    const int ch = u >> 3, k0 = (u & 7)*64;
    const float* src = w2 + ((size_t)ch*512 + k0)*64;
    #pragma unroll
    for (int j = 0; j < 4; ++j) {
      const int uu = t + j*256;
      const int k = uu >> 4, seg = uu & 15;
      const float4 v = ((const float4*)src)[(size_t)k*16 + seg];
      sm.tile[(seg*4+0)*72 + k] = (_Float16)v.x;
      sm.tile[(seg*4+1)*72 + k] = (_Float16)v.y;
      sm.tile[(seg*4+2)*72 + k] = (_Float16)v.z;
      sm.tile[(seg*4+3)*72 + k] = (_Float16)v.w;
    }
    __syncthreads();
    _Float16* dst = w2T + (size_t)ch*32768;
    #pragma unroll
    for (int j = 0; j < 2; ++j) {
      const int uu = t + j*256;
      const int f = uu >> 3, seg = uu & 7;
      const f16x8 o = *(const f16x8*)&sm.tile[f*72 + seg*8];
      const int kk = k0 + seg*8;
      const int chunk = (f >> 4)*64 + ((seg & 3))*16 + (f & 15);   // (kk>>3)&3 == seg&3
      *(f16x8*)(dst + (size_t)(kk >> 5)*2048 + chunk*8) = o;
    }
  } else {
    const int g = (bx - 1152)*4 + w;
    const int base = g*32;
    #pragma unroll
    for (int jb = 0; jb < 4; ++jb) {
      int vals[8];
      #pragma unroll
      for (int i = 0; i < 8; ++i) {
        const int idx = base + jb*8 + i;
        const int b = idx >> 14;
        const int n = (idx >> 4) & (NN - 1);
        const int wd = idx & 15;
        vals[i] = adj[((size_t)b*NN + n)*NN + wd*64 + lane];
      }
      #pragma unroll
      for (int i = 0; i < 8; ++i) {
        const int idx = base + jb*8 + i;
        const int n = (idx >> 4) & (NN - 1);
        const int m = (idx & 15)*64 + lane;
        const unsigned long long bits = __ballot((vals[i] != 0) || (m == n));
        if (lane == 0) bmg[idx] = bits;
      }
    }
  }
}

// ---------------- Monster v7: conflict-free LDS reads (lane-linear) ----------
template<int LAYER>
__global__ __launch_bounds__(1024, 4) void attn_monster(
    const _Float16* __restrict__ HpTin, const float* __restrict__ s_arr,
    const float* __restrict__ d_arr, const unsigned long long* __restrict__ bmg,
    const _Float16* __restrict__ w2T, const float* __restrict__ asrc2,
    const float* __restrict__ adst2,
    _Float16* __restrict__ HpT2, float* __restrict__ s2, float* __restrict__ d2,
    float* __restrict__ out)
{
  __shared__ union {
    struct {
      __align__(16) _Float16 stg[2][16][2048];  // 128 KB B staging
      __align__(16) float dstg[16][512];        // 32 KB per-wave d slice
    } kl;                                       // k-loop phase: 160 KB
    struct {
      float obuf[2][8][16][68];                 // 69.6 KB partial O per kh
      float dsb[2][8][16];                      // row-sum partials per kh
      float spb[8][16], sdb[8][16];             // layer-2 score partials
      __align__(16) _Float16 x1[8192];          // 16 KB elu'd concat (permuted chunks)
      __align__(16) _Float16 wstg[2][16][1024]; // 64 KB proj2 W staging
    } l1;
    struct { float mbuf[16][64]; float dsb[2][8][16]; } l2;
  } sm;

  const int bc = blockIdx.x;             // 0..3
  const int r0 = blockIdx.y * 16;
  const int t = threadIdx.x;
  const int wv = t >> 6;                 // 0..15
  const int h  = wv >> 1, kh = wv & 1;   // head, k-half
  const int lane = t & 63;
  const int colr = lane & 15, quad = lane >> 4;
  const int bch = bc*HH + h;
  const int b = bc >> 1, c = bc & 1;

  // full-range maxd (identical in both waves of a head -> shared offset)
  const float* dg = d_arr + (size_t)bch*NN;
  const float4* dg4 = (const float4*)dg;
  float mxl = -1e30f;
  #pragma unroll
  for (int j = 0; j < 4; ++j) {
    const float4 v = dg4[lane + 64*j];
    mxl = fmaxf(fmaxf(v.x, v.y), fmaxf(fmaxf(v.z, v.w), mxl));
  }
  #pragma unroll
  for (int off = 1; off < 64; off <<= 1) mxl = fmaxf(mxl, __shfl_xor(mxl, off));
  const float maxd = mxl;

  const int r = r0 + colr;
  const float s = s_arr[(size_t)bch*NN + r];
  const float so = s + maxd;
  const float offs = fmaxf(so, 0.2f*so);       // >= lrelu(s+d) for all d
  const float sA = s - offs, sB = 0.2f*s - offs;

  unsigned long long m[8];
  {
    const unsigned long long* bm = bmg + ((size_t)b*NN + r)*16 + kh*8;
    #pragma unroll
    for (int j = 0; j < 8; ++j) m[j] = bm[j];
  }

  // stage this wave's d half-slice (2 KB) into LDS: wave-private
  {
    const float4* s4 = (const float4*)(dg + kh*512);
    const float4 v0 = s4[lane*2];
    const float4 v1 = s4[lane*2 + 1];
    *(float4*)&sm.kl.dstg[wv][lane*8]     = v0;
    *(float4*)&sm.kl.dstg[wv][lane*8 + 4] = v1;
  }

  const _Float16* strip = HpTin + (size_t)bch*65536 + (size_t)kh*32768;

  f32x4 acc[4];
  f32x4 accs = {0.f,0.f,0.f,0.f};
  #pragma unroll
  for (int ft = 0; ft < 4; ++ft) acc[ft] = (f32x4){0.f,0.f,0.f,0.f};
  f16x8 ones;
  #pragma unroll
  for (int i = 0; i < 8; ++i) ones[i] = (_Float16)1.f;

#define STAGE_B(tt) { \
    const _Float16* gs_ = strip + (tt)*2048 + lane*8; \
    _Float16* ls_ = &sm.kl.stg[(tt) & 1][wv][0]; \
    gl_lds16(gs_,        ls_); \
    gl_lds16(gs_ + 512,  ls_ + 512); \
    gl_lds16(gs_ + 1024, ls_ + 1024); \
    gl_lds16(gs_ + 1536, ls_ + 1536); }

  STAGE_B(0);

  #pragma unroll
  for (int ks = 0; ks < 16; ++ks) {
    if (ks < 15) {
      asm volatile("s_waitcnt lgkmcnt(0)" ::: "memory");
      STAGE_B(ks + 1);
      asm volatile("s_waitcnt vmcnt(4)" ::: "memory");   // stage(ks) landed (exact)
    } else {
      asm volatile("s_waitcnt vmcnt(0)" ::: "memory");
    }

    // lane-linear fragment reads: chunk ft*64 + lane -> zero bank conflicts
    f16x8 Bc[4];
    #pragma unroll
    for (int ft = 0; ft < 4; ++ft)
      Bc[ft] = *(const f16x8*)&sm.kl.stg[ks & 1][wv][ft*512 + lane*8];

    const float* dls = &sm.kl.dstg[wv][ks*32 + quad*8];
    const float4 da0 = *(const float4*)dls;
    const float4 da1 = *(const float4*)(dls + 4);

    __builtin_amdgcn_s_setprio(1);
    const unsigned mb = (unsigned)((m[ks >> 1] >> ((ks & 1)*32 + quad*8)) & 0xFFull);
    const float dd[8] = {da0.x, da0.y, da0.z, da0.w, da1.x, da1.y, da1.z, da1.w};
    union { f16x8 v; h16x2 hh[4]; } A;
    #pragma unroll
    for (int jp = 0; jp < 4; ++jp) {
      float p[2];
      #pragma unroll
      for (int jj = 0; jj < 2; ++jj) {
        const int j = jp*2 + jj;
        const float dj = dd[j];
        const float l = fmaxf(sA + dj, fmaf(0.2f, dj, sB));  // log2e-scaled domain
        p[jj] = ((mb >> j) & 1u) ? fexp2(l) : 0.f;
      }
      A.hh[jp] = __builtin_amdgcn_cvt_pkrtz(p[0], p[1]);
    }
    #pragma unroll
    for (int ft = 0; ft < 4; ++ft)
      acc[ft] = __builtin_amdgcn_mfma_f32_16x16x32_f16(A.v, Bc[ft], acc[ft], 0, 0, 0);
    accs = __builtin_amdgcn_mfma_f32_16x16x32_f16(A.v, ones, accs, 0, 0, 0);
    __builtin_amdgcn_s_setprio(0);
  }
#undef STAGE_B

  __syncthreads();                        // staging buffers dead from here on

  if (LAYER == 1) {
    if (t < 256) (&sm.l1.spb[0][0])[t] = 0.f;
    #pragma unroll
    for (int ft = 0; ft < 4; ++ft)
      #pragma unroll
      for (int i = 0; i < 4; ++i)
        sm.l1.obuf[kh][h][quad*4 + i][ft*16 + colr] = acc[ft][i];
    if (colr == 0) {
      #pragma unroll
      for (int i = 0; i < 4; ++i) sm.l1.dsb[kh][h][quad*4 + i] = accs[i];
    }
    __syncthreads();

    // x1 = elu(O/dsum), stored in permuted chunks: k = hp*64+f0+j ->
    // chunk = (hp*2 + (f0>>5))*64 + ((f0>>3)&3)*16 + row
    {
      const int row = t >> 6;
      const int hp  = (t >> 3) & 7;
      const int f0  = (t & 7)*8;
      const float invd = 1.f / (sm.l1.dsb[0][hp][row] + sm.l1.dsb[1][hp][row]);
      const float* ob0 = &sm.l1.obuf[0][hp][row][f0];
      const float* ob1 = &sm.l1.obuf[1][hp][row][f0];
      f16x8 xo;
      #pragma unroll
      for (int j = 0; j < 8; ++j) {
        float v = (ob0[j] + ob1[j]) * invd;
        v = v > 0.f ? v : expm1f(v);
        xo[j] = (_Float16)v;
      }
      const int chunk = (hp*2 + (f0 >> 5))*64 + ((f0 >> 3) & 3)*16 + row;
      *(f16x8*)&sm.l1.x1[chunk*8] = xo;
    }
    __syncthreads();

    // proj2: wave (h,kh) computes f-tiles fb..fb+1 of head h
    const int fb = kh*2;
    const _Float16* wstrip = w2T + (size_t)(c*HH + h)*32768 + fb*512;
    f32x4 acc2[2];
    acc2[0] = (f32x4){0.f,0.f,0.f,0.f}; acc2[1] = (f32x4){0.f,0.f,0.f,0.f};

#define STAGE_W(tt) { \
    const _Float16* gs_ = wstrip + (tt)*2048 + lane*8; \
    _Float16* ls_ = &sm.l1.wstg[(tt) & 1][wv][0]; \
    gl_lds16(gs_,       ls_); \
    gl_lds16(gs_ + 512, ls_ + 512); }

    STAGE_W(0);
    #pragma unroll
    for (int k2 = 0; k2 < 16; ++k2) {
      if (k2 < 15) {
        asm volatile("s_waitcnt lgkmcnt(0)" ::: "memory");
        STAGE_W(k2 + 1);
        asm volatile("s_waitcnt vmcnt(2)" ::: "memory");
      } else {
        asm volatile("s_waitcnt vmcnt(0)" ::: "memory");
      }
      // lane-linear: staged chunks (fb..fb+2)*64 -> local chunk u*64 + lane
      f16x8 Wc[2];
      #pragma unroll
      for (int u = 0; u < 2; ++u)
        Wc[u] = *(const f16x8*)&sm.l1.wstg[k2 & 1][wv][u*512 + lane*8];
      const f16x8 Af = *(const f16x8*)&sm.l1.x1[(k2*64 + lane)*8];
      #pragma unroll
      for (int u = 0; u < 2; ++u)
        acc2[u] = __builtin_amdgcn_mfma_f32_16x16x32_f16(Af, Wc[u], acc2[u], 0, 0, 0);
    }
#undef STAGE_W

    float af[2], bfv[2];
    #pragma unroll
    for (int u = 0; u < 2; ++u) {
      af[u]  = asrc2[(c*HH + h)*64 + (fb+u)*16 + colr];
      bfv[u] = adst2[(c*HH + h)*64 + (fb+u)*16 + colr];
    }
    #pragma unroll
    for (int i = 0; i < 4; ++i) {
      float ps = 0.f, pd = 0.f;
      #pragma unroll
      for (int u = 0; u < 2; ++u) {
        const float v = acc2[u][i];
        const float ex = __expf(2.f*v);
        const float th = 1.f - 2.f/(ex + 1.f);
        ps += th * af[u]; pd += th * bfv[u];
      }
      #pragma unroll
      for (int off = 1; off < 16; off <<= 1) {
        ps += __shfl_xor(ps, off);
        pd += __shfl_xor(pd, off);
      }
      if (colr == 0) {
        atomicAdd(&sm.l1.spb[h][quad*4 + i], ps);
        atomicAdd(&sm.l1.sdb[h][quad*4 + i], pd);
      }
    }
    // HpT2 permuted-tile write: f = (fb+u)*16+colr, k = (r0&16) + quad*4 + i
    _Float16* H2 = HpT2 + (size_t)bch*65536 + (size_t)(r0 >> 5)*2048;
    const int kgb = 2*((r0 >> 4) & 1) + (quad >> 1);
    #pragma unroll
    for (int u = 0; u < 2; ++u) {
      f16x4 hv;
      #pragma unroll
      for (int i = 0; i < 4; ++i) hv[i] = (_Float16)acc2[u][i];
      const int chunk = (fb+u)*64 + kgb*16 + colr;
      *(f16x4*)(H2 + chunk*8 + (quad & 1)*4) = hv;
    }
    __syncthreads();
    if (t < 128) {
      const int hp = t >> 4, rr = t & 15;
      s2[(size_t)(bc*HH + hp)*NN + r0 + rr] = sm.l1.spb[hp][rr] * LOG2E;
      d2[(size_t)(bc*HH + hp)*NN + r0 + rr] = sm.l1.sdb[hp][rr] * LOG2E;
    }
  } else {
    sm.l2.mbuf[t >> 6][t & 63] = 0.f;
    if (colr == 0) {
      #pragma unroll
      for (int i = 0; i < 4; ++i) sm.l2.dsb[kh][h][quad*4 + i] = accs[i];
    }
    __syncthreads();
    float inv[4];
    #pragma unroll
    for (int i = 0; i < 4; ++i)
      inv[i] = 0.125f / (sm.l2.dsb[0][h][quad*4 + i] + sm.l2.dsb[1][h][quad*4 + i]);
    #pragma unroll
    for (int ft = 0; ft < 4; ++ft)
      #pragma unroll
      for (int i = 0; i < 4; ++i)
        atomicAdd(&sm.l2.mbuf[quad*4 + i][ft*16 + colr], acc[ft][i] * inv[i]);
    __syncthreads();
    out[((size_t)bc*NN + r0 + wv)*64 + lane] = sm.l2.mbuf[wv][lane];
  }
}

extern "C" void kernel_launch(void* const* d_in, const int* in_sizes, int n_in,
                              void* d_out, int out_size, void* d_ws, size_t ws_size,
                              hipStream_t stream)
{
  const float* x   = (const float*)d_in[0];
  const int*   adj = (const int*)d_in[1];
  const float* w1  = (const float*)d_in[2];
  const float* as1 = (const float*)d_in[3];
  const float* ad1 = (const float*)d_in[4];
  const float* w2  = (const float*)d_in[5];
  const float* as2 = (const float*)d_in[6];
  const float* ad2 = (const float*)d_in[7];

  char* w8 = (char*)d_ws;
  _Float16* HpT  = (_Float16*)(w8);                         // 4 MB  permuted tiles
  _Float16* HpT2 = (_Float16*)(w8 + (4u<<20));              // 4 MB  permuted tiles
  _Float16* w2T  = (_Float16*)(w8 + (8u<<20));              // 1 MB  permuted tiles
  float* s_v  = (float*)(w8 + (10u<<20));                   // 128 KB (log2e-scaled)
  float* d_v  = (float*)(w8 + (10u<<20) + SVN*4);           // 128 KB
  float* s2_v = (float*)(w8 + (10u<<20) + SVN*8);           // 128 KB
  float* d2_v = (float*)(w8 + (10u<<20) + SVN*12);          // 128 KB
  unsigned long long* bmg = (unsigned long long*)(w8 + (10u<<20) + SVN*16);  // 256 KB

  proj1_fused<<<1408, 256, 0, stream>>>(x, adj, w1, w2, as1, ad1, w2T, bmg, HpT, s_v, d_v);
  attn_monster<1><<<dim3(4, 64), 1024, 0, stream>>>(HpT, s_v, d_v, bmg, w2T, as2, ad2,
                                                    HpT2, s2_v, d2_v, (float*)d_out);
  attn_monster<2><<<dim3(4, 64), 1024, 0, stream>>>(HpT2, s2_v, d2_v, bmg, w2T, as2, ad2,
                                                    HpT2, s2_v, d2_v, (float*)d_out);
}

// Round 11
// 138.006 us; speedup vs baseline: 1.1010x; 1.0948x over previous
//
#include <hip/hip_runtime.h>

#define BB 2
#define CC 2
#define NN 1024
#define HH 8
#define BCHN 32
#define SVN  (BCHN*NN)       // 32768
#define LOG2E 1.44269504f

typedef _Float16 f16x8 __attribute__((ext_vector_type(8)));
typedef _Float16 f16x4 __attribute__((ext_vector_type(4)));
typedef __fp16 h16x2 __attribute__((ext_vector_type(2)));   // cvt_pkrtz native type
typedef float f32x4 __attribute__((ext_vector_type(4)));

__device__ __forceinline__ float fexp2(float x) {
  float r; asm("v_exp_f32 %0, %1" : "=v"(r) : "v"(x)); return r;
}

// Direct global->LDS staging. LDS dest = wave-uniform base + lane*16B.
__device__ __forceinline__ void gl_lds16(const _Float16* g, _Float16* l) {
  __builtin_amdgcn_global_load_lds(
      (const __attribute__((address_space(1))) void*)g,
      (__attribute__((address_space(3))) void*)l, 16, 0, 0);
}

// Hp/w2T tiles are 4KB [64 f][32 k] with PERMUTED in-tile order:
//   16B-chunk(f,k) = (f>>4)*64 + ((k>>3)&3)*16 + (f&15), elem j = k&7.
// => MFMA fragment read for (ft, lane) is chunk ft*64 + lane: lane-linear, 0 conflicts.

// ---------------- Fused layer-1 projection + prep (unchanged from r10) ----------
__global__ __launch_bounds__(256) void proj1_fused(
    const float* __restrict__ x, const int* __restrict__ adj,
    const float* __restrict__ w1, const float* __restrict__ w2,
    const float* __restrict__ asrc, const float* __restrict__ adst,
    _Float16* __restrict__ w2T, unsigned long long* __restrict__ bmg,
    _Float16* __restrict__ HpT, float* __restrict__ s_out, float* __restrict__ d_out)
{
  __shared__ union {
    __align__(16) _Float16 tile[64*72];
    struct { float sp[4][32]; float sd[4][32]; } pr;
  } sm;
  const int bx = blockIdx.x;
  const int t = threadIdx.x;
  const int w = t >> 6, lane = t & 63;
  const int colr = lane & 15, quad = lane >> 4;

  if (bx < 1024) {
    const int bch = bx & 31;
    const int row0 = (bx >> 5) * 32;
    const int h = bch & 7; const int bc = bch >> 3; const int c = bc & 1;

    const float* Ar0 = x + ((size_t)bc*NN + row0 + colr)*64;
    const float* Ar1 = Ar0 + (size_t)16*64;
    const float* Bw  = w1 + ((size_t)(c*HH + h))*64*64 + w*16 + colr;

    f32x4 acc0 = {0.f,0.f,0.f,0.f}, acc1 = {0.f,0.f,0.f,0.f};
    #pragma unroll
    for (int kb = 0; kb < 64; kb += 32) {
      const float4 pa0 = *(const float4*)(Ar0 + kb + quad*8);
      const float4 pa1 = *(const float4*)(Ar0 + kb + quad*8 + 4);
      const float4 pb0 = *(const float4*)(Ar1 + kb + quad*8);
      const float4 pb1 = *(const float4*)(Ar1 + kb + quad*8 + 4);
      float bv[8];
      #pragma unroll
      for (int j = 0; j < 8; ++j) bv[j] = Bw[(size_t)(kb + quad*8 + j)*64];
      f16x8 a0, a1, bf;
      a0[0]=(_Float16)pa0.x; a0[1]=(_Float16)pa0.y; a0[2]=(_Float16)pa0.z; a0[3]=(_Float16)pa0.w;
      a0[4]=(_Float16)pa1.x; a0[5]=(_Float16)pa1.y; a0[6]=(_Float16)pa1.z; a0[7]=(_Float16)pa1.w;
      a1[0]=(_Float16)pb0.x; a1[1]=(_Float16)pb0.y; a1[2]=(_Float16)pb0.z; a1[3]=(_Float16)pb0.w;
      a1[4]=(_Float16)pb1.x; a1[5]=(_Float16)pb1.y; a1[6]=(_Float16)pb1.z; a1[7]=(_Float16)pb1.w;
      #pragma unroll
      for (int j = 0; j < 8; ++j) bf[j] = (_Float16)bv[j];
      acc0 = __builtin_amdgcn_mfma_f32_16x16x32_f16(a0, bf, acc0, 0, 0, 0);
      acc1 = __builtin_amdgcn_mfma_f32_16x16x32_f16(a1, bf, acc1, 0, 0, 0);
    }

    const float af  = asrc[(c*HH + h)*64 + w*16 + colr];
    const float bf_ = adst[(c*HH + h)*64 + w*16 + colr];
    _Float16* HT = HpT + (size_t)bch*65536 + (size_t)(row0 >> 5)*2048;

    #pragma unroll
    for (int mt = 0; mt < 2; ++mt) {
      const f32x4 a = mt ? acc1 : acc0;
      f16x4 hv;
      #pragma unroll
      for (int i = 0; i < 4; ++i) {
        const float v = a[i];
        hv[i] = (_Float16)v;
        const float ex = __expf(2.f*v);
        const float th = 1.f - 2.f/(ex + 1.f);         // tanh(v)
        float ps = th * af, pd = th * bf_;
        #pragma unroll
        for (int off = 1; off < 16; off <<= 1) {
          ps += __shfl_xor(ps, off);
          pd += __shfl_xor(pd, off);
        }
        if (colr == 0) {
          sm.pr.sp[w][mt*16 + quad*4 + i] = ps;
          sm.pr.sd[w][mt*16 + quad*4 + i] = pd;
        }
      }
      const int chunk = w*64 + (mt*2 + (quad >> 1))*16 + colr;
      *(f16x4*)(HT + chunk*8 + (quad & 1)*4) = hv;
    }
    __syncthreads();
    if (t < 32) {
      const float sv = sm.pr.sp[0][t] + sm.pr.sp[1][t] + sm.pr.sp[2][t] + sm.pr.sp[3][t];
      const float dv = sm.pr.sd[0][t] + sm.pr.sd[1][t] + sm.pr.sd[2][t] + sm.pr.sd[3][t];
      s_out[bch*NN + row0 + t] = sv * LOG2E;
      d_out[bch*NN + row0 + t] = dv * LOG2E;
    }
  } else if (bx < 1152) {
    const int u = bx - 1024;
    const int ch = u >> 3, k0 = (u & 7)*64;
    const float* src = w2 + ((size_t)ch*512 + k0)*64;
    #pragma unroll
    for (int j = 0; j < 4; ++j) {
      const int uu = t + j*256;
      const int k = uu >> 4, seg = uu & 15;
      const float4 v = ((const float4*)src)[(size_t)k*16 + seg];
      sm.tile[(seg*4+0)*72 + k] = (_Float16)v.x;
      sm.tile[(seg*4+1)*72 + k] = (_Float16)v.y;
      sm.tile[(seg*4+2)*72 + k] = (_Float16)v.z;
      sm.tile[(seg*4+3)*72 + k] = (_Float16)v.w;
    }
    __syncthreads();
    _Float16* dst = w2T + (size_t)ch*32768;
    #pragma unroll
    for (int j = 0; j < 2; ++j) {
      const int uu = t + j*256;
      const int f = uu >> 3, seg = uu & 7;
      const f16x8 o = *(const f16x8*)&sm.tile[f*72 + seg*8];
      const int kk = k0 + seg*8;
      const int chunk = (f >> 4)*64 + ((seg & 3))*16 + (f & 15);
      *(f16x8*)(dst + (size_t)(kk >> 5)*2048 + chunk*8) = o;
    }
  } else {
    const int g = (bx - 1152)*4 + w;
    const int base = g*32;
    #pragma unroll
    for (int jb = 0; jb < 4; ++jb) {
      int vals[8];
      #pragma unroll
      for (int i = 0; i < 8; ++i) {
        const int idx = base + jb*8 + i;
        const int b = idx >> 14;
        const int n = (idx >> 4) & (NN - 1);
        const int wd = idx & 15;
        vals[i] = adj[((size_t)b*NN + n)*NN + wd*64 + lane];
      }
      #pragma unroll
      for (int i = 0; i < 8; ++i) {
        const int idx = base + jb*8 + i;
        const int n = (idx >> 4) & (NN - 1);
        const int m = (idx & 15)*64 + lane;
        const unsigned long long bits = __ballot((vals[i] != 0) || (m == n));
        if (lane == 0) bmg[idx] = bits;
      }
    }
  }
}

// ---------------- Monster (LAYER 1 only): unchanged from r10 ----------
template<int LAYER>
__global__ __launch_bounds__(1024, 4) void attn_monster(
    const _Float16* __restrict__ HpTin, const float* __restrict__ s_arr,
    const float* __restrict__ d_arr, const unsigned long long* __restrict__ bmg,
    const _Float16* __restrict__ w2T, const float* __restrict__ asrc2,
    const float* __restrict__ adst2,
    _Float16* __restrict__ HpT2, float* __restrict__ s2, float* __restrict__ d2,
    float* __restrict__ out)
{
  __shared__ union {
    struct {
      __align__(16) _Float16 stg[2][16][2048];  // 128 KB B staging
      __align__(16) float dstg[16][512];        // 32 KB per-wave d slice
    } kl;
    struct {
      float obuf[2][8][16][68];
      float dsb[2][8][16];
      float spb[8][16], sdb[8][16];
      __align__(16) _Float16 x1[8192];
      __align__(16) _Float16 wstg[2][16][1024];
    } l1;
    struct { float mbuf[16][64]; float dsb[2][8][16]; } l2;
  } sm;

  const int bc = blockIdx.x;
  const int r0 = blockIdx.y * 16;
  const int t = threadIdx.x;
  const int wv = t >> 6;
  const int h  = wv >> 1, kh = wv & 1;
  const int lane = t & 63;
  const int colr = lane & 15, quad = lane >> 4;
  const int bch = bc*HH + h;
  const int b = bc >> 1, c = bc & 1;

  const float* dg = d_arr + (size_t)bch*NN;
  const float4* dg4 = (const float4*)dg;
  float mxl = -1e30f;
  #pragma unroll
  for (int j = 0; j < 4; ++j) {
    const float4 v = dg4[lane + 64*j];
    mxl = fmaxf(fmaxf(v.x, v.y), fmaxf(fmaxf(v.z, v.w), mxl));
  }
  #pragma unroll
  for (int off = 1; off < 64; off <<= 1) mxl = fmaxf(mxl, __shfl_xor(mxl, off));
  const float maxd = mxl;

  const int r = r0 + colr;
  const float s = s_arr[(size_t)bch*NN + r];
  const float so = s + maxd;
  const float offs = fmaxf(so, 0.2f*so);
  const float sA = s - offs, sB = 0.2f*s - offs;

  unsigned long long m[8];
  {
    const unsigned long long* bm = bmg + ((size_t)b*NN + r)*16 + kh*8;
    #pragma unroll
    for (int j = 0; j < 8; ++j) m[j] = bm[j];
  }

  {
    const float4* s4 = (const float4*)(dg + kh*512);
    const float4 v0 = s4[lane*2];
    const float4 v1 = s4[lane*2 + 1];
    *(float4*)&sm.kl.dstg[wv][lane*8]     = v0;
    *(float4*)&sm.kl.dstg[wv][lane*8 + 4] = v1;
  }

  const _Float16* strip = HpTin + (size_t)bch*65536 + (size_t)kh*32768;

  f32x4 acc[4];
  f32x4 accs = {0.f,0.f,0.f,0.f};
  #pragma unroll
  for (int ft = 0; ft < 4; ++ft) acc[ft] = (f32x4){0.f,0.f,0.f,0.f};
  f16x8 ones;
  #pragma unroll
  for (int i = 0; i < 8; ++i) ones[i] = (_Float16)1.f;

#define STAGE_B(tt) { \
    const _Float16* gs_ = strip + (tt)*2048 + lane*8; \
    _Float16* ls_ = &sm.kl.stg[(tt) & 1][wv][0]; \
    gl_lds16(gs_,        ls_); \
    gl_lds16(gs_ + 512,  ls_ + 512); \
    gl_lds16(gs_ + 1024, ls_ + 1024); \
    gl_lds16(gs_ + 1536, ls_ + 1536); }

  STAGE_B(0);

  #pragma unroll
  for (int ks = 0; ks < 16; ++ks) {
    if (ks < 15) {
      asm volatile("s_waitcnt lgkmcnt(0)" ::: "memory");
      STAGE_B(ks + 1);
      asm volatile("s_waitcnt vmcnt(4)" ::: "memory");
    } else {
      asm volatile("s_waitcnt vmcnt(0)" ::: "memory");
    }

    f16x8 Bc[4];
    #pragma unroll
    for (int ft = 0; ft < 4; ++ft)
      Bc[ft] = *(const f16x8*)&sm.kl.stg[ks & 1][wv][ft*512 + lane*8];

    const float* dls = &sm.kl.dstg[wv][ks*32 + quad*8];
    const float4 da0 = *(const float4*)dls;
    const float4 da1 = *(const float4*)(dls + 4);

    __builtin_amdgcn_s_setprio(1);
    const unsigned mb = (unsigned)((m[ks >> 1] >> ((ks & 1)*32 + quad*8)) & 0xFFull);
    const float dd[8] = {da0.x, da0.y, da0.z, da0.w, da1.x, da1.y, da1.z, da1.w};
    union { f16x8 v; h16x2 hh[4]; } A;
    #pragma unroll
    for (int jp = 0; jp < 4; ++jp) {
      float p[2];
      #pragma unroll
      for (int jj = 0; jj < 2; ++jj) {
        const int j = jp*2 + jj;
        const float dj = dd[j];
        const float l = fmaxf(sA + dj, fmaf(0.2f, dj, sB));
        p[jj] = ((mb >> j) & 1u) ? fexp2(l) : 0.f;
      }
      A.hh[jp] = __builtin_amdgcn_cvt_pkrtz(p[0], p[1]);
    }
    #pragma unroll
    for (int ft = 0; ft < 4; ++ft)
      acc[ft] = __builtin_amdgcn_mfma_f32_16x16x32_f16(A.v, Bc[ft], acc[ft], 0, 0, 0);
    accs = __builtin_amdgcn_mfma_f32_16x16x32_f16(A.v, ones, accs, 0, 0, 0);
    __builtin_amdgcn_s_setprio(0);
  }
#undef STAGE_B

  __syncthreads();

  if (LAYER == 1) {
    if (t < 256) (&sm.l1.spb[0][0])[t] = 0.f;
    #pragma unroll
    for (int ft = 0; ft < 4; ++ft)
      #pragma unroll
      for (int i = 0; i < 4; ++i)
        sm.l1.obuf[kh][h][quad*4 + i][ft*16 + colr] = acc[ft][i];
    if (colr == 0) {
      #pragma unroll
      for (int i = 0; i < 4; ++i) sm.l1.dsb[kh][h][quad*4 + i] = accs[i];
    }
    __syncthreads();

    {
      const int row = t >> 6;
      const int hp  = (t >> 3) & 7;
      const int f0  = (t & 7)*8;
      const float invd = 1.f / (sm.l1.dsb[0][hp][row] + sm.l1.dsb[1][hp][row]);
      const float* ob0 = &sm.l1.obuf[0][hp][row][f0];
      const float* ob1 = &sm.l1.obuf[1][hp][row][f0];
      f16x8 xo;
      #pragma unroll
      for (int j = 0; j < 8; ++j) {
        float v = (ob0[j] + ob1[j]) * invd;
        v = v > 0.f ? v : expm1f(v);
        xo[j] = (_Float16)v;
      }
      const int chunk = (hp*2 + (f0 >> 5))*64 + ((f0 >> 3) & 3)*16 + row;
      *(f16x8*)&sm.l1.x1[chunk*8] = xo;
    }
    __syncthreads();

    const int fb = kh*2;
    const _Float16* wstrip = w2T + (size_t)(c*HH + h)*32768 + fb*512;
    f32x4 acc2[2];
    acc2[0] = (f32x4){0.f,0.f,0.f,0.f}; acc2[1] = (f32x4){0.f,0.f,0.f,0.f};

#define STAGE_W(tt) { \
    const _Float16* gs_ = wstrip + (tt)*2048 + lane*8; \
    _Float16* ls_ = &sm.l1.wstg[(tt) & 1][wv][0]; \
    gl_lds16(gs_,       ls_); \
    gl_lds16(gs_ + 512, ls_ + 512); }

    STAGE_W(0);
    #pragma unroll
    for (int k2 = 0; k2 < 16; ++k2) {
      if (k2 < 15) {
        asm volatile("s_waitcnt lgkmcnt(0)" ::: "memory");
        STAGE_W(k2 + 1);
        asm volatile("s_waitcnt vmcnt(2)" ::: "memory");
      } else {
        asm volatile("s_waitcnt vmcnt(0)" ::: "memory");
      }
      f16x8 Wc[2];
      #pragma unroll
      for (int u = 0; u < 2; ++u)
        Wc[u] = *(const f16x8*)&sm.l1.wstg[k2 & 1][wv][u*512 + lane*8];
      const f16x8 Af = *(const f16x8*)&sm.l1.x1[(k2*64 + lane)*8];
      #pragma unroll
      for (int u = 0; u < 2; ++u)
        acc2[u] = __builtin_amdgcn_mfma_f32_16x16x32_f16(Af, Wc[u], acc2[u], 0, 0, 0);
    }
#undef STAGE_W

    float af[2], bfv[2];
    #pragma unroll
    for (int u = 0; u < 2; ++u) {
      af[u]  = asrc2[(c*HH + h)*64 + (fb+u)*16 + colr];
      bfv[u] = adst2[(c*HH + h)*64 + (fb+u)*16 + colr];
    }
    #pragma unroll
    for (int i = 0; i < 4; ++i) {
      float ps = 0.f, pd = 0.f;
      #pragma unroll
      for (int u = 0; u < 2; ++u) {
        const float v = acc2[u][i];
        const float ex = __expf(2.f*v);
        const float th = 1.f - 2.f/(ex + 1.f);
        ps += th * af[u]; pd += th * bfv[u];
      }
      #pragma unroll
      for (int off = 1; off < 16; off <<= 1) {
        ps += __shfl_xor(ps, off);
        pd += __shfl_xor(pd, off);
      }
      if (colr == 0) {
        atomicAdd(&sm.l1.spb[h][quad*4 + i], ps);
        atomicAdd(&sm.l1.sdb[h][quad*4 + i], pd);
      }
    }
    _Float16* H2 = HpT2 + (size_t)bch*65536 + (size_t)(r0 >> 5)*2048;
    const int kgb = 2*((r0 >> 4) & 1) + (quad >> 1);
    #pragma unroll
    for (int u = 0; u < 2; ++u) {
      f16x4 hv;
      #pragma unroll
      for (int i = 0; i < 4; ++i) hv[i] = (_Float16)acc2[u][i];
      const int chunk = (fb+u)*64 + kgb*16 + colr;
      *(f16x4*)(H2 + chunk*8 + (quad & 1)*4) = hv;
    }
    __syncthreads();
    if (t < 128) {
      const int hp = t >> 4, rr = t & 15;
      s2[(size_t)(bc*HH + hp)*NN + r0 + rr] = sm.l1.spb[hp][rr] * LOG2E;
      d2[(size_t)(bc*HH + hp)*NN + r0 + rr] = sm.l1.sdb[hp][rr] * LOG2E;
    }
  }
}

// ---------------- attn2_coop: 64 rows/block, BLOCK-COOPERATIVE B staging ----------
// grid (bch=32, rt=16) = 512 blocks (2/CU); 4 waves; wave wv owns rows wv*16..+16.
// All waves share one k-walk: per K-step ONE 4KB tile staged coop (1 gl_lds/wave),
// consumed by all 4 waves (4x byte reuse vs private streams). vmcnt(1) + raw
// s_barrier per step keeps the next stage in flight (never vmcnt(0) mid-loop).
__global__ __launch_bounds__(256) void attn2_coop(
    const _Float16* __restrict__ HpT2, const float* __restrict__ s_arr,
    const float* __restrict__ d_arr, const unsigned long long* __restrict__ bmg,
    _Float16* __restrict__ XB)
{
  __shared__ struct {
    __align__(16) _Float16 stg[2][2048];   // 8 KB: 2 slots of one 4KB tile
    __align__(16) float dstg[1024];        // 4 KB full d[bch]
    float pw[4][16][68];                   // 17.4 KB epilogue transpose
  } sm;
  const int bch = blockIdx.x;
  const int r0 = blockIdx.y * 64;
  const int t = threadIdx.x;
  const int wv = t >> 6, lane = t & 63;
  const int colr = lane & 15, quad = lane >> 4;
  const int b = bch >> 4;                  // bch / (CC*HH)

  // maxd over full d[bch]
  const float* dg = d_arr + (size_t)bch*NN;
  const float4* dg4 = (const float4*)dg;
  float mxl = -1e30f;
  #pragma unroll
  for (int j = 0; j < 4; ++j) {
    const float4 v = dg4[lane + 64*j];
    mxl = fmaxf(fmaxf(v.x, v.y), fmaxf(fmaxf(v.z, v.w), mxl));
  }
  #pragma unroll
  for (int off = 1; off < 64; off <<= 1) mxl = fmaxf(mxl, __shfl_xor(mxl, off));
  const float maxd = mxl;

  // stage d to LDS (cross-wave -> barrier below)
  *(float4*)&sm.dstg[t*4] = dg4[t];

  const int r = r0 + wv*16 + colr;         // this lane's row
  const float s = s_arr[(size_t)bch*NN + r];
  const float so = s + maxd;
  const float offs = fmaxf(so, 0.2f*so);
  const float sA = s - offs, sB = 0.2f*s - offs;

  unsigned long long m[16];
  {
    const unsigned long long* bm = bmg + ((size_t)b*NN + r)*16;
    #pragma unroll
    for (int j = 0; j < 16; ++j) m[j] = bm[j];
  }

  const _Float16* strip = HpT2 + (size_t)bch*65536;

  f32x4 acc[4];
  f32x4 accs = {0.f,0.f,0.f,0.f};
  #pragma unroll
  for (int ft = 0; ft < 4; ++ft) acc[ft] = (f32x4){0.f,0.f,0.f,0.f};
  f16x8 ones;
  #pragma unroll
  for (int i = 0; i < 8; ++i) ones[i] = (_Float16)1.f;

  // drain prologue VMEM (so in-loop vmcnt counts stage ops only), publish dstg
  asm volatile("s_waitcnt vmcnt(0) lgkmcnt(0)" ::: "memory");
  __builtin_amdgcn_s_barrier();

  // coop stage: wave wv stages quarter wv of the 4KB tile (1 gl_lds = 1KB)
#define STAGE_T(tt) \
    gl_lds16(strip + (size_t)(tt)*2048 + wv*512 + lane*8, &sm.stg[(tt) & 1][wv*512]);

  STAGE_T(0);
  asm volatile("s_waitcnt vmcnt(0)" ::: "memory");
  __builtin_amdgcn_s_barrier();            // tile 0 visible to all waves

  #pragma unroll 4
  for (int ks = 0; ks < 32; ++ks) {
    if (ks < 31) STAGE_T(ks + 1);          // flies across this step's compute

    // lane-linear fragment reads from the shared tile (permuted layout)
    f16x8 Bc[4];
    #pragma unroll
    for (int ft = 0; ft < 4; ++ft)
      Bc[ft] = *(const f16x8*)&sm.stg[ks & 1][ft*512 + lane*8];
    const float* dls = &sm.dstg[ks*32 + quad*8];
    const float4 da0 = *(const float4*)dls;
    const float4 da1 = *(const float4*)(dls + 4);
    asm volatile("s_waitcnt lgkmcnt(0)" ::: "memory");
    __builtin_amdgcn_sched_barrier(0);     // rule 18: pin MFMA after ds_read

    __builtin_amdgcn_s_setprio(1);
    const unsigned mb = (unsigned)((m[ks >> 1] >> ((ks & 1)*32 + quad*8)) & 0xFFull);
    const float dd[8] = {da0.x, da0.y, da0.z, da0.w, da1.x, da1.y, da1.z, da1.w};
    union { f16x8 v; h16x2 hh[4]; } A;
    #pragma unroll
    for (int jp = 0; jp < 4; ++jp) {
      float p[2];
      #pragma unroll
      for (int jj = 0; jj < 2; ++jj) {
        const int j = jp*2 + jj;
        const float dj = dd[j];
        const float l = fmaxf(sA + dj, fmaf(0.2f, dj, sB));  // log2e-scaled domain
        p[jj] = ((mb >> j) & 1u) ? fexp2(l) : 0.f;
      }
      A.hh[jp] = __builtin_amdgcn_cvt_pkrtz(p[0], p[1]);
    }
    #pragma unroll
    for (int ft = 0; ft < 4; ++ft)
      acc[ft] = __builtin_amdgcn_mfma_f32_16x16x32_f16(A.v, Bc[ft], acc[ft], 0, 0, 0);
    accs = __builtin_amdgcn_mfma_f32_16x16x32_f16(A.v, ones, accs, 0, 0, 0);
    __builtin_amdgcn_s_setprio(0);

    // my share of stage(ks+1) landed (<=1 outstanding); others' via barrier.
    // My ds_reads of slot[ks&1] are complete (lgkmcnt(0) above), so the
    // overwrite of slot[(ks+1)&1] next iteration is safe for all waves.
    if (ks < 31) asm volatile("s_waitcnt vmcnt(0)" ::: "memory");
    __builtin_amdgcn_s_barrier();
  }
#undef STAGE_T

  // epilogue: normalize + /8, per-wave LDS transpose, coalesced f16 writes
  float inv[4];
  #pragma unroll
  for (int i = 0; i < 4; ++i) inv[i] = 0.125f / accs[i];
  float (*pw)[68] = sm.pw[wv];
  #pragma unroll
  for (int ft = 0; ft < 4; ++ft)
    #pragma unroll
    for (int i = 0; i < 4; ++i)
      pw[quad*4 + i][ft*16 + colr] = acc[ft][i] * inv[i];
  // wave-private read-back (same-wave LDS ordering; compiler inserts lgkm waits)
  const int row = lane >> 2, f0 = (lane & 3)*16;
  f16x8 o0, o1;
  #pragma unroll
  for (int j = 0; j < 8; ++j) {
    o0[j] = (_Float16)pw[row][f0 + j];
    o1[j] = (_Float16)pw[row][f0 + 4 + ((j + 4) & 7)];
  }
  // simpler: re-read linearly
  #pragma unroll
  for (int j = 0; j < 8; ++j) o0[j] = (_Float16)pw[row][f0 + j];
  #pragma unroll
  for (int j = 0; j < 8; ++j) o1[j] = (_Float16)pw[row][f0 + 8 + j];
  _Float16* dst = XB + ((size_t)bch*NN + r0 + wv*16 + row)*64 + f0;
  *(f16x8*)dst = o0;
  *(f16x8*)(dst + 8) = o1;
}

// ---------------- Mean over heads (f16 in) -> fp32 out ----------------
__global__ __launch_bounds__(256) void reduce_heads(
    const _Float16* __restrict__ out2, float* __restrict__ out)
{
  const int o = blockIdx.x*256 + threadIdx.x;
  const int f = o & 63;
  const int n = (o >> 6) & (NN - 1);
  const int bc = o >> 16;
  float acc = 0.f;
  #pragma unroll
  for (int h = 0; h < HH; ++h)
    acc += (float)out2[(((size_t)bc*HH + h)*NN + n)*64 + f];
  out[o] = acc;   // attn2_coop already folded the 1/8
}

extern "C" void kernel_launch(void* const* d_in, const int* in_sizes, int n_in,
                              void* d_out, int out_size, void* d_ws, size_t ws_size,
                              hipStream_t stream)
{
  const float* x   = (const float*)d_in[0];
  const int*   adj = (const int*)d_in[1];
  const float* w1  = (const float*)d_in[2];
  const float* as1 = (const float*)d_in[3];
  const float* ad1 = (const float*)d_in[4];
  const float* w2  = (const float*)d_in[5];
  const float* as2 = (const float*)d_in[6];
  const float* ad2 = (const float*)d_in[7];

  char* w8 = (char*)d_ws;
  _Float16* HpT  = (_Float16*)(w8);                         // 4 MB  permuted tiles
  _Float16* HpT2 = (_Float16*)(w8 + (4u<<20));              // 4 MB  permuted tiles
  _Float16* w2T  = (_Float16*)(w8 + (8u<<20));              // 1 MB  permuted tiles
  float* s_v  = (float*)(w8 + (10u<<20));                   // 128 KB (log2e-scaled)
  float* d_v  = (float*)(w8 + (10u<<20) + SVN*4);           // 128 KB
  float* s2_v = (float*)(w8 + (10u<<20) + SVN*8);           // 128 KB
  float* d2_v = (float*)(w8 + (10u<<20) + SVN*12);          // 128 KB
  unsigned long long* bmg = (unsigned long long*)(w8 + (10u<<20) + SVN*16);  // 256 KB
  _Float16* XB = (_Float16*)(w8 + (16u<<20));               // 4 MB  O2 per-head

  proj1_fused<<<1408, 256, 0, stream>>>(x, adj, w1, w2, as1, ad1, w2T, bmg, HpT, s_v, d_v);
  attn_monster<1><<<dim3(4, 64), 1024, 0, stream>>>(HpT, s_v, d_v, bmg, w2T, as2, ad2,
                                                    HpT2, s2_v, d2_v, (float*)d_out);
  attn2_coop<<<dim3(BCHN, NN/64), 256, 0, stream>>>(HpT2, s2_v, d2_v, bmg, XB);
  reduce_heads<<<dim3((unsigned)(out_size/256)), 256, 0, stream>>>(XB, (float*)d_out);
}